// Round 1
// baseline (1654.676 us; speedup 1.0000x reference)
//
#include <hip/hip_runtime.h>

#define B_    1024
#define S_    50
#define L_    20
#define HID_  128
#define NOUT  100001

typedef __attribute__((ext_vector_type(8))) short bh8;   // 8 bf16 (4 VGPRs)
typedef __attribute__((ext_vector_type(4))) float fx4;   // MFMA C/D

__device__ __forceinline__ unsigned short f2bf(float x){
  unsigned u = __float_as_uint(x);
  unsigned r = (u + 0x7FFFu + ((u >> 16) & 1u)) >> 16;   // RNE
  return (unsigned short)r;
}
__device__ __forceinline__ float bf2f(unsigned short h){
  return __uint_as_float(((unsigned)h) << 16);
}
__device__ __forceinline__ float sigm(float x){ return 1.f/(1.f + __expf(-x)); }
__device__ __forceinline__ float tanh_(float x){ return 1.f - 2.f/(__expf(2.f*x) + 1.f); }

// ---------------------------------------------------------------------------
// Weight prep: swizzle LSTM weights into per-lane B-fragment order, hi/lo bf16.
// Layout: [layer(2)][nt(32)][kt(8)][plane(2)][lane(64)][8 bf16]
// B-frag for 16x16x32: n = lane&15, k = (lane>>4)*8 + j.  n = nt*16+?, K=256 is
// concat [x(128) | h(128)] -> W_ih cols then W_hh cols. Also bias = b_ih+b_hh.
__global__ __launch_bounds__(256) void prep_lstm_w(
    const float* __restrict__ Wih0, const float* __restrict__ Whh0,
    const float* __restrict__ bih0, const float* __restrict__ bhh0,
    const float* __restrict__ Wih1, const float* __restrict__ Whh1,
    const float* __restrict__ bih1, const float* __restrict__ bhh1,
    short* __restrict__ wsw, float* __restrict__ wsbias){
  int tid = blockIdx.x*256 + threadIdx.x;       // 32768 total
  if (tid < 1024){
    int l = tid >> 9, n = tid & 511;
    wsbias[l*512 + n] = l ? (bih1[n] + bhh1[n]) : (bih0[n] + bhh0[n]);
  }
  if (tid >= 32768) return;
  int lane = tid & 63;
  int kt   = (tid >> 6) & 7;
  int nt   = (tid >> 9) & 31;
  int l    = tid >> 14;
  const float* Wih = l ? Wih1 : Wih0;
  const float* Whh = l ? Whh1 : Whh0;
  int n = nt*16 + (lane & 15);
  int kbase = kt*32 + (lane >> 4)*8;
  size_t base_hi = (((((size_t)l*32 + nt)*8 + kt)*2 + 0)*64 + lane)*8;
  size_t base_lo = (((((size_t)l*32 + nt)*8 + kt)*2 + 1)*64 + lane)*8;
  for (int j = 0; j < 8; j++){
    int k = kbase + j;
    float w = (k < 128) ? Wih[n*128 + k] : Whh[n*128 + (k - 128)];
    unsigned short hi = f2bf(w);
    float rem = w - bf2f(hi);
    wsw[base_hi + j] = (short)hi;
    wsw[base_lo + j] = (short)f2bf(rem);
  }
}

// W2 -> bf16, padded to 100016 rows (zeros).
__global__ __launch_bounds__(256) void prep_w2(const float* __restrict__ W2,
                                               short* __restrict__ out){
  long i = (long)blockIdx.x*256 + threadIdx.x;  // 100016*64 = 6,401,024
  if (i >= 100016L*64) return;
  long row = i >> 6;
  float v = (row < NOUT) ? W2[i] : 0.f;
  out[i] = (short)f2bf(v);
}

// ---------------------------------------------------------------------------
// Features: x[s][b][128] = [prod_mean(64) | cat_mean(32) | ts(16) | uf(16)]
__global__ __launch_bounds__(128) void features(
    const int* __restrict__ pidx, const int* __restrict__ cidx,
    const float* __restrict__ age, const float* __restrict__ ts,
    const float* __restrict__ gender,
    const float* __restrict__ embp, const float* __restrict__ embc,
    const float* __restrict__ Wts, const float* __restrict__ bts,
    const float* __restrict__ Wuf, const float* __restrict__ bufv,
    float* __restrict__ xout){
  int bs = blockIdx.x;            // b*S_ + s
  int b  = bs / S_;
  int s  = bs % S_;
  int t  = threadIdx.x;
  __shared__ int pi[L_], ci[L_];
  if (t < L_)            pi[t]       = pidx[(size_t)bs*L_ + t];
  else if (t < 2*L_)     ci[t - L_]  = cidx[(size_t)bs*L_ + (t - L_)];
  __syncthreads();
  float v;
  if (t < 64){
    float a = 0.f;
    #pragma unroll 4
    for (int l = 0; l < L_; l++) a += embp[(size_t)pi[l]*64 + t];
    v = a * (1.f/20.f);
  } else if (t < 96){
    int j = t - 64; float a = 0.f;
    #pragma unroll 4
    for (int l = 0; l < L_; l++) a += embc[(size_t)ci[l]*32 + j];
    v = a * (1.f/20.f);
  } else if (t < 112){
    int j = t - 96;
    v = ts[bs]*Wts[j] + bts[j];
  } else {
    int j = t - 112;
    v = age[b]*Wuf[j*2] + gender[b]*Wuf[j*2 + 1] + bufv[j];
  }
  xout[((size_t)s*B_ + b)*128 + t] = v;
}

// ---------------------------------------------------------------------------
// 2-layer LSTM, 50 steps, 16 batch rows per block (64 blocks, 4 waves).
// Wave w owns N-tiles {w+4i}: i=2m+z -> gate m, j-block (w+4z)*16 -> wave holds
// matching i/f/g/o slices, c-state lives in registers. h relayout via LDS.
// hi/lo bf16 split (3 MFMAs) == fp32-accurate.
__global__ __launch_bounds__(256) void lstm_kernel(
    const float* __restrict__ xin, const short* __restrict__ wsw,
    const float* __restrict__ wsbias, float* __restrict__ hlast){
  __shared__ float XH0[16][260];   // [x_t(128) | h0(128)] + pad
  __shared__ float XH1[16][260];   // [h0_t(128) | h1(128)] + pad
  const int tid  = threadIdx.x;
  const int w    = tid >> 6, lane = tid & 63;
  const int col  = lane & 15, quad = lane >> 4;
  const int b0   = blockIdx.x * 16;
  const bh8* wp  = (const bh8*)wsw;

  for (int i = tid; i < 2048; i += 256){
    XH0[i >> 7][128 + (i & 127)] = 0.f;
    XH1[i >> 7][128 + (i & 127)] = 0.f;
  }
  fx4 cst[2][2];
  #pragma unroll
  for (int l = 0; l < 2; l++)
    #pragma unroll
    for (int z = 0; z < 2; z++) cst[l][z] = (fx4){0.f, 0.f, 0.f, 0.f};
  __syncthreads();

  for (int t = 0; t < S_; t++){
    const float* xp = xin + ((size_t)t*B_ + b0)*128;
    for (int i = tid; i < 2048; i += 256)
      XH0[i >> 7][i & 127] = xp[(i >> 7)*128 + (i & 127)];
    __syncthreads();

    for (int l = 0; l < 2; l++){
      float (*XH)[260] = l ? XH1 : XH0;
      // A-fragment prep: A[m=col][k = kt*32 + quad*8 + j], hi/lo split
      bh8 ahi[8], alo[8];
      #pragma unroll
      for (int kt = 0; kt < 8; kt++){
        const float* p = &XH[col][kt*32 + quad*8];
        bh8 hv, lv;
        #pragma unroll
        for (int j = 0; j < 8; j++){
          float x = p[j];
          unsigned short hb = f2bf(x);
          hv[j] = (short)hb;
          lv[j] = (short)f2bf(x - bf2f(hb));
        }
        ahi[kt] = hv; alo[kt] = lv;
      }
      __syncthreads();   // all A-frags read before h writes below

      fx4 acc[8];
      #pragma unroll
      for (int i = 0; i < 8; i++){
        const int nt = w + 4*i;
        const float bz = wsbias[l*512 + nt*16 + col];
        fx4 a = {bz, bz, bz, bz};
        const size_t base = (size_t)(l*32 + nt)*1024 + lane;
        #pragma unroll
        for (int kt = 0; kt < 8; kt++){
          bh8 bh = wp[base + kt*128];
          bh8 bl = wp[base + kt*128 + 64];
          a = __builtin_amdgcn_mfma_f32_16x16x32_bf16(ahi[kt], bh, a, 0, 0, 0);
          a = __builtin_amdgcn_mfma_f32_16x16x32_bf16(alo[kt], bh, a, 0, 0, 0);
          a = __builtin_amdgcn_mfma_f32_16x16x32_bf16(ahi[kt], bl, a, 0, 0, 0);
        }
        acc[i] = a;
      }
      // gate update; D layout: col = lane&15 (gate dim), row = quad*4 + r (batch)
      #pragma unroll
      for (int z = 0; z < 2; z++){
        fx4 ig = acc[z], fg = acc[2+z], gg = acc[4+z], og = acc[6+z];
        const int jb = (w + 4*z)*16 + col;
        #pragma unroll
        for (int r = 0; r < 4; r++){
          float cv = sigm(fg[r]) * cst[l][z][r] + sigm(ig[r]) * tanh_(gg[r]);
          cst[l][z][r] = cv;
          float hv = sigm(og[r]) * tanh_(cv);
          int row = quad*4 + r;
          if (l == 0){ XH1[row][jb] = hv; XH0[row][128 + jb] = hv; }
          else       { XH1[row][128 + jb] = hv; }
        }
      }
      __syncthreads();
    }
  }
  for (int i = tid; i < 2048; i += 256)
    hlast[((size_t)(b0 + (i >> 7)))*128 + (i & 127)] = XH1[i >> 7][128 + (i & 127)];
}

// ---------------------------------------------------------------------------
// hidden = relu(h_last @ W1^T + b1) -> bf16 [1024][64]
__global__ __launch_bounds__(256) void head1(
    const float* __restrict__ hl, const float* __restrict__ W1,
    const float* __restrict__ b1, short* __restrict__ hidden_bf){
  int o = blockIdx.x*256 + threadIdx.x;   // 65536
  int row = o >> 6, c = o & 63;
  const float* h  = hl + (size_t)row*128;
  const float* wr = W1 + (size_t)c*128;
  float a = b1[c];
  #pragma unroll 8
  for (int k = 0; k < 128; k++) a += h[k]*wr[k];
  a = fmaxf(a, 0.f);
  hidden_bf[o] = (short)f2bf(a);
}

// logits = hidden @ W2^T + b2 : one 16x16 MFMA tile per wave per n-tile.
__global__ __launch_bounds__(256) void head2(
    const short* __restrict__ hid, const short* __restrict__ w2,
    const float* __restrict__ b2, float* __restrict__ out){
  int wgid = blockIdx.x*4 + (threadIdx.x >> 6);
  int lane = threadIdx.x & 63, col = lane & 15, quad = lane >> 4;
  int mt = wgid & 63;        // M tile (16 rows of 1024)
  int nc = wgid >> 6;        // chunk of 8 N-tiles; 782 chunks
  if (nc >= 782) return;
  const bh8* hp = (const bh8*)hid;
  bh8 a0 = hp[(mt*16 + col)*8 + quad];       // k in [0,32)
  bh8 a1 = hp[(mt*16 + col)*8 + 4 + quad];   // k in [32,64)
  const bh8* wpt = (const bh8*)w2;
  for (int i = 0; i < 8; i++){
    long nt = (long)nc*8 + i;
    if (nt >= 6251) break;                   // 100016/16 tiles
    long nbase = nt*16;
    bh8 bb0 = wpt[(nbase + col)*8 + quad];
    bh8 bb1 = wpt[(nbase + col)*8 + 4 + quad];
    fx4 a = {0.f, 0.f, 0.f, 0.f};
    a = __builtin_amdgcn_mfma_f32_16x16x32_bf16(a0, bb0, a, 0, 0, 0);
    a = __builtin_amdgcn_mfma_f32_16x16x32_bf16(a1, bb1, a, 0, 0, 0);
    long n = nbase + col;
    if (n < NOUT){
      float bias = b2[n];
      #pragma unroll
      for (int r = 0; r < 4; r++){
        long row = mt*16 + quad*4 + r;
        out[row*(long)NOUT + n] = a[r] + bias;
      }
    }
  }
}

// ---------------------------------------------------------------------------
extern "C" void kernel_launch(void* const* d_in, const int* in_sizes, int n_in,
                              void* d_out, int out_size, void* d_ws, size_t ws_size,
                              hipStream_t stream){
  const int*   prod = (const int*)  d_in[0];
  const int*   cat  = (const int*)  d_in[1];
  const float* age  = (const float*)d_in[2];
  const float* ts   = (const float*)d_in[3];
  const float* gen  = (const float*)d_in[4];
  const float* embp = (const float*)d_in[5];
  const float* embc = (const float*)d_in[6];
  const float* Wts  = (const float*)d_in[7];
  const float* bts  = (const float*)d_in[8];
  const float* Wuf  = (const float*)d_in[9];
  const float* bufv = (const float*)d_in[10];
  const float* Wih0 = (const float*)d_in[11];
  const float* Whh0 = (const float*)d_in[12];
  const float* bih0 = (const float*)d_in[13];
  const float* bhh0 = (const float*)d_in[14];
  const float* Wih1 = (const float*)d_in[15];
  const float* Whh1 = (const float*)d_in[16];
  const float* bih1 = (const float*)d_in[17];
  const float* bhh1 = (const float*)d_in[18];
  const float* W1   = (const float*)d_in[19];
  const float* b1   = (const float*)d_in[20];
  const float* W2   = (const float*)d_in[21];
  const float* b2   = (const float*)d_in[22];
  float* out = (float*)d_out;

  char* ws = (char*)d_ws;
  float* ws_x    = (float*)(ws);               // [50][1024][128] f32 : 26,214,400 B
  short* ws_w    = (short*)(ws + 26214400);    // swizzled LSTM weights: 1,048,576 B
  float* ws_bias = (float*)(ws + 27262976);    // [2][512] f32 : 4,096 B
  float* ws_hl   = (float*)(ws + 27267072);    // h_last [1024][128] f32 : 524,288 B
  short* ws_hid  = (short*)(ws + 27791360);    // hidden bf16 [1024][64] : 131,072 B
  short* ws_w2   = (short*)(ws + 27922432);    // W2 bf16 [100016][64] : 12,802,048 B

  prep_lstm_w<<<128, 256, 0, stream>>>(Wih0, Whh0, bih0, bhh0,
                                       Wih1, Whh1, bih1, bhh1, ws_w, ws_bias);
  prep_w2<<<25004, 256, 0, stream>>>(W2, ws_w2);
  features<<<B_*S_, 128, 0, stream>>>(prod, cat, age, ts, gen, embp, embc,
                                      Wts, bts, Wuf, bufv, ws_x);
  lstm_kernel<<<64, 256, 0, stream>>>(ws_x, ws_w, ws_bias, ws_hl);
  head1<<<256, 256, 0, stream>>>(ws_hl, W1, b1, ws_hid);
  head2<<<12512, 256, 0, stream>>>(ws_hid, ws_w2, b2, out);
}

// Round 2
// 1143.435 us; speedup vs baseline: 1.4471x; 1.4471x over previous
//
#include <hip/hip_runtime.h>

#define B_    1024
#define S_    50
#define L_    20
#define NOUT  100001

typedef __attribute__((ext_vector_type(8))) short bh8;   // 8 bf16 (4 VGPRs)
typedef __attribute__((ext_vector_type(4))) float fx4;   // MFMA C/D

__device__ __forceinline__ unsigned short f2bf(float x){
  unsigned u = __float_as_uint(x);
  unsigned r = (u + 0x7FFFu + ((u >> 16) & 1u)) >> 16;   // RNE
  return (unsigned short)r;
}
__device__ __forceinline__ float bf2f(unsigned short h){
  return __uint_as_float(((unsigned)h) << 16);
}
__device__ __forceinline__ float sigm(float x){ return 1.f/(1.f + __expf(-x)); }
__device__ __forceinline__ float tanh_(float x){ return 1.f - 2.f/(__expf(2.f*x) + 1.f); }

// split x into bf16 hi + bf16 lo (hi+lo == x to ~2^-17 rel)
__device__ __forceinline__ void frag_convert_row(const float* src, bh8& hv, bh8& lv){
  #pragma unroll
  for (int j = 0; j < 8; j++){
    float x = src[j];
    unsigned short hb = f2bf(x);
    hv[j] = (short)hb;
    lv[j] = (short)f2bf(x - bf2f(hb));
  }
}

// ---------------------------------------------------------------------------
// LSTM weight prep: single bf16 plane in per-lane B-fragment order.
// Layout: [layer(2)][nt(32)][kt(8)][lane(64)][8 bf16]
// B-frag (16x16x32): n = nt*16 + (lane&15), k = kt*32 + (lane>>4)*8 + j.
// K=256 = [x(128) | h(128)] -> W_ih cols then W_hh cols. bias = b_ih + b_hh.
__global__ __launch_bounds__(256) void prep_lstm_w(
    const float* __restrict__ Wih0, const float* __restrict__ Whh0,
    const float* __restrict__ bih0, const float* __restrict__ bhh0,
    const float* __restrict__ Wih1, const float* __restrict__ Whh1,
    const float* __restrict__ bih1, const float* __restrict__ bhh1,
    short* __restrict__ wsw, float* __restrict__ wsbias){
  int tid = blockIdx.x*256 + threadIdx.x;       // 32768 total
  if (tid < 1024){
    int l = tid >> 9, n = tid & 511;
    wsbias[l*512 + n] = l ? (bih1[n] + bhh1[n]) : (bih0[n] + bhh0[n]);
  }
  if (tid >= 32768) return;
  int lane = tid & 63;
  int kt   = (tid >> 6) & 7;
  int nt   = (tid >> 9) & 31;
  int l    = tid >> 14;
  const float* Wih = l ? Wih1 : Wih0;
  const float* Whh = l ? Whh1 : Whh0;
  int n = nt*16 + (lane & 15);
  int kbase = kt*32 + (lane >> 4)*8;
  size_t base = ((((size_t)l*32 + nt)*8 + kt)*64 + lane)*8;
  for (int j = 0; j < 8; j++){
    int k = kbase + j;
    float w = (k < 128) ? Wih[n*128 + k] : Whh[n*128 + (k - 128)];
    wsw[base + j] = (short)f2bf(w);
  }
}

// W2 -> bf16, padded to 100016 rows (zeros).
__global__ __launch_bounds__(256) void prep_w2(const float* __restrict__ W2,
                                               short* __restrict__ out){
  long i = (long)blockIdx.x*256 + threadIdx.x;  // 100016*64 = 6,401,024
  if (i >= 100016L*64) return;
  long row = i >> 6;
  float v = (row < NOUT) ? W2[i] : 0.f;
  out[i] = (short)f2bf(v);
}

// ---------------------------------------------------------------------------
// Features -> x in A-fragment order, bf16 hi/lo planes.
// xfrag layout: [s(50)][bt(64)][plane(2)][kt(4)][lane(64)][8 bf16]
// Block = (bt, s): 16 batch rows x 128 features.
__global__ __launch_bounds__(256) void features(
    const int* __restrict__ pidx, const int* __restrict__ cidx,
    const float* __restrict__ age, const float* __restrict__ ts,
    const float* __restrict__ gender,
    const float* __restrict__ embp, const float* __restrict__ embc,
    const float* __restrict__ Wts, const float* __restrict__ bts,
    const float* __restrict__ Wuf, const float* __restrict__ bufv,
    short* __restrict__ xfrag){
  const int bx = blockIdx.x;
  const int bt = bx & 63, s = bx >> 6;
  const int b0 = bt*16;
  const int tid = threadIdx.x;
  __shared__ int pi[320], ci[320];
  __shared__ __align__(16) float XF[16][132];
  for (int i = tid; i < 640; i += 256){
    if (i < 320){
      int row = i/20, l = i - row*20;
      pi[i] = pidx[((size_t)(b0+row)*S_ + s)*L_ + l];
    } else {
      int j = i - 320;
      int row = j/20, l = j - row*20;
      ci[j] = cidx[((size_t)(b0+row)*S_ + s)*L_ + l];
    }
  }
  __syncthreads();
  const int m = tid >> 4, fg = tid & 15;
  float a[8];
  if (fg < 8){
    int f0 = fg*8;
    float4 s0 = {0,0,0,0}, s1 = {0,0,0,0};
    for (int l = 0; l < L_; l++){
      const float4* p = (const float4*)(embp + (size_t)pi[m*20+l]*64 + f0);
      float4 u = p[0], v = p[1];
      s0.x += u.x; s0.y += u.y; s0.z += u.z; s0.w += u.w;
      s1.x += v.x; s1.y += v.y; s1.z += v.z; s1.w += v.w;
    }
    a[0]=s0.x*0.05f; a[1]=s0.y*0.05f; a[2]=s0.z*0.05f; a[3]=s0.w*0.05f;
    a[4]=s1.x*0.05f; a[5]=s1.y*0.05f; a[6]=s1.z*0.05f; a[7]=s1.w*0.05f;
  } else if (fg < 12){
    int f0 = (fg-8)*8;
    float4 s0 = {0,0,0,0}, s1 = {0,0,0,0};
    for (int l = 0; l < L_; l++){
      const float4* p = (const float4*)(embc + (size_t)ci[m*20+l]*32 + f0);
      float4 u = p[0], v = p[1];
      s0.x += u.x; s0.y += u.y; s0.z += u.z; s0.w += u.w;
      s1.x += v.x; s1.y += v.y; s1.z += v.z; s1.w += v.w;
    }
    a[0]=s0.x*0.05f; a[1]=s0.y*0.05f; a[2]=s0.z*0.05f; a[3]=s0.w*0.05f;
    a[4]=s1.x*0.05f; a[5]=s1.y*0.05f; a[6]=s1.z*0.05f; a[7]=s1.w*0.05f;
  } else if (fg < 14){
    int j0 = (fg-12)*8;
    float tv = ts[(size_t)(b0+m)*S_ + s];
    #pragma unroll
    for (int e = 0; e < 8; e++) a[e] = tv*Wts[j0+e] + bts[j0+e];
  } else {
    int j0 = (fg-14)*8;
    float av = age[b0+m], gv = gender[b0+m];
    #pragma unroll
    for (int e = 0; e < 8; e++){
      int j = j0+e;
      a[e] = av*Wuf[2*j] + gv*Wuf[2*j+1] + bufv[j];
    }
  }
  {
    int f0 = fg*8;
    *(float4*)&XF[m][f0]   = (float4){a[0],a[1],a[2],a[3]};
    *(float4*)&XF[m][f0+4] = (float4){a[4],a[5],a[6],a[7]};
  }
  __syncthreads();
  // phase 2: emit fragment-order hi/lo planes
  const int kt = tid >> 6, ls = tid & 63;
  const int mm = ls & 15, a2 = ls >> 4;
  bh8 hv, lv;
  frag_convert_row(&XF[mm][kt*32 + a2*8], hv, lv);
  size_t ob = ((((size_t)s*64 + bt)*2 + 0)*4 + kt)*512 + (size_t)ls*8;
  *(bh8*)(xfrag + ob)        = hv;   // plane 0 (hi)
  *(bh8*)(xfrag + ob + 2048) = lv;   // plane 1 (lo)
}

// ---------------------------------------------------------------------------
// 2-layer LSTM, 50 steps. 64 blocks x 512 thr (8 waves). 16 batch rows/block.
// Wave w owns j-slice [w*16, w*16+16) for all 4 gates (nt = g*8 + w) ->
// c-state in registers. A operands live in LDS as bf16 hi/lo fragments;
// 2-term split MFMA (Ahi*B + Alo*B) keeps activations fp32-exact vs bf16 W.
// Fused epilogue: hidden = relu(h_last @ W1^T + b1) -> bf16.
__global__ __launch_bounds__(512, 2) void lstm_kernel(
    const short* __restrict__ xfrag, const short* __restrict__ wsw,
    const float* __restrict__ wsbias,
    const float* __restrict__ W1, const float* __restrict__ b1,
    short* __restrict__ hidden_bf){
  __shared__ __align__(16) short XA0hi[2][2048], XA0lo[2][2048]; // x frags, dbuf
  __shared__ __align__(16) short HA0hi[2048],   HA0lo[2048];     // h0 frags (kt 0..3 ~ k 128..255)
  __shared__ __align__(16) short A1hi[4096],    A1lo[4096];      // layer1 A: [h0 | h1]
  __shared__ __align__(16) float XHf[16][132];                   // fp32 h scratch
  const int tid  = threadIdx.x;
  const int w    = tid >> 6, lane = tid & 63;
  const int col  = lane & 15, quad = lane >> 4;
  const int bt   = blockIdx.x;
  const int plane = tid >> 8, sl = tid & 255;
  const bh8* wp = (const bh8*)wsw;

  for (int i = tid; i < 2048; i += 512){
    HA0hi[i] = 0; HA0lo[i] = 0;
    A1hi[2048 + i] = 0; A1lo[2048 + i] = 0;
  }
  float bz[2][4];
  #pragma unroll
  for (int l = 0; l < 2; l++)
    #pragma unroll
    for (int g = 0; g < 4; g++)
      bz[l][g] = wsbias[l*512 + (g*8 + w)*16 + col];
  fx4 c0 = {0,0,0,0}, c1 = {0,0,0,0};
  // stage x(0)
  {
    float4 v = *(const float4*)(xfrag + ((size_t)bt*2 + plane)*2048 + (size_t)sl*8);
    *(float4*)((plane ? XA0lo[0] : XA0hi[0]) + sl*8) = v;
  }

  for (int t = 0; t < S_; t++){
    __syncthreads();                                   // bar_a
    const int tb = t & 1;
    int tp = (t+1 < S_) ? t+1 : S_-1;
    float4 pf = *(const float4*)(xfrag + (((size_t)tp*64 + bt)*2 + plane)*2048 + (size_t)sl*8);

    // ---- layer 0 ----
    fx4 acc[4];
    #pragma unroll
    for (int g = 0; g < 4; g++) acc[g] = (fx4){bz[0][g], bz[0][g], bz[0][g], bz[0][g]};
    #pragma unroll
    for (int kt = 0; kt < 8; kt++){
      const short* ph = (kt < 4) ? &XA0hi[tb][kt*512 + lane*8] : &HA0hi[(kt-4)*512 + lane*8];
      const short* pl = (kt < 4) ? &XA0lo[tb][kt*512 + lane*8] : &HA0lo[(kt-4)*512 + lane*8];
      bh8 ah = *(const bh8*)ph;
      bh8 al = *(const bh8*)pl;
      #pragma unroll
      for (int g = 0; g < 4; g++){
        bh8 bb = wp[(size_t)((g*8 + w)*8 + kt)*64 + lane];
        acc[g] = __builtin_amdgcn_mfma_f32_16x16x32_bf16(ah, bb, acc[g], 0, 0, 0);
        acc[g] = __builtin_amdgcn_mfma_f32_16x16x32_bf16(al, bb, acc[g], 0, 0, 0);
      }
    }
    #pragma unroll
    for (int r = 0; r < 4; r++){
      float cc = sigm(acc[1][r])*c0[r] + sigm(acc[0][r])*tanh_(acc[2][r]);
      c0[r] = cc;
      XHf[quad*4 + r][w*16 + col] = sigm(acc[3][r])*tanh_(cc);
    }
    __syncthreads();                                   // bar_b
    if (tid < 256){                                    // h0 -> frags
      const int kt4 = tid >> 6, ls2 = tid & 63;
      const int mm = ls2 & 15, a2 = ls2 >> 4;
      bh8 hv, lv;
      frag_convert_row(&XHf[mm][kt4*32 + a2*8], hv, lv);
      *(bh8*)&A1hi[kt4*512 + ls2*8] = hv;              // layer1 x-part
      *(bh8*)&A1lo[kt4*512 + ls2*8] = lv;
      *(bh8*)&HA0hi[kt4*512 + ls2*8] = hv;             // layer0 h-part (t+1)
      *(bh8*)&HA0lo[kt4*512 + ls2*8] = lv;
    }
    __syncthreads();                                   // bar_c

    // ---- layer 1 ----
    #pragma unroll
    for (int g = 0; g < 4; g++) acc[g] = (fx4){bz[1][g], bz[1][g], bz[1][g], bz[1][g]};
    #pragma unroll
    for (int kt = 0; kt < 8; kt++){
      bh8 ah = *(const bh8*)&A1hi[kt*512 + lane*8];
      bh8 al = *(const bh8*)&A1lo[kt*512 + lane*8];
      #pragma unroll
      for (int g = 0; g < 4; g++){
        bh8 bb = wp[(size_t)((32 + g*8 + w)*8 + kt)*64 + lane];
        acc[g] = __builtin_amdgcn_mfma_f32_16x16x32_bf16(ah, bb, acc[g], 0, 0, 0);
        acc[g] = __builtin_amdgcn_mfma_f32_16x16x32_bf16(al, bb, acc[g], 0, 0, 0);
      }
    }
    // park the x(t+1) prefetch (disjoint buffer from this step's readers)
    *(float4*)((plane ? XA0lo[(t+1)&1] : XA0hi[(t+1)&1]) + sl*8) = pf;
    #pragma unroll
    for (int r = 0; r < 4; r++){
      float cc = sigm(acc[1][r])*c1[r] + sigm(acc[0][r])*tanh_(acc[2][r]);
      c1[r] = cc;
      XHf[quad*4 + r][w*16 + col] = sigm(acc[3][r])*tanh_(cc);
    }
    __syncthreads();                                   // bar_d
    if (tid < 256){                                    // h1 -> layer1 h-part frags
      const int kt4 = tid >> 6, ls2 = tid & 63;
      const int mm = ls2 & 15, a2 = ls2 >> 4;
      bh8 hv, lv;
      frag_convert_row(&XHf[mm][kt4*32 + a2*8], hv, lv);
      *(bh8*)&A1hi[(4+kt4)*512 + ls2*8] = hv;
      *(bh8*)&A1lo[(4+kt4)*512 + ls2*8] = lv;
    }
  }
  // XHf holds h1(t=49), stable since bar_d. Fused head1.
  #pragma unroll
  for (int e = 0; e < 2; e++){
    int mm = (tid >> 6)*2 + e;
    int cc = tid & 63;
    float s = b1[cc];
    #pragma unroll 8
    for (int k = 0; k < 128; k++) s += XHf[mm][k]*W1[cc*128 + k];
    s = fmaxf(s, 0.f);
    hidden_bf[(size_t)(bt*16 + mm)*64 + cc] = (short)f2bf(s);
  }
}

// ---------------------------------------------------------------------------
// logits = hidden @ W2^T + b2. Block = (chunk of 32 n-tiles) x (one m-tile);
// results re-staged through LDS so global stores are 512B-contiguous rows.
__global__ __launch_bounds__(256) void head2(
    const short* __restrict__ hid, const short* __restrict__ w2,
    const float* __restrict__ b2, float* __restrict__ out){
  __shared__ __align__(16) float HS[4][16][132];
  const int tid = threadIdx.x;
  const int w = tid >> 6, lane = tid & 63;
  const int col = lane & 15, quad = lane >> 4;
  const int mt = blockIdx.x & 63;
  const int chunk = blockIdx.x >> 6;       // 196 chunks
  const bh8* hp = (const bh8*)hid;
  bh8 a0 = hp[(size_t)(mt*16 + col)*8 + quad];
  bh8 a1 = hp[(size_t)(mt*16 + col)*8 + 4 + quad];
  const bh8* wpt = (const bh8*)w2;
  #pragma unroll
  for (int i = 0; i < 8; i++){
    int nt = chunk*32 + w*8 + i;
    if (nt < 6251){
      int n = nt*16 + col;
      bh8 b0v = wpt[(size_t)n*8 + quad];
      bh8 b1v = wpt[(size_t)n*8 + 4 + quad];
      fx4 a = {0.f,0.f,0.f,0.f};
      a = __builtin_amdgcn_mfma_f32_16x16x32_bf16(a0, b0v, a, 0, 0, 0);
      a = __builtin_amdgcn_mfma_f32_16x16x32_bf16(a1, b1v, a, 0, 0, 0);
      float bias = (n < NOUT) ? b2[n] : 0.f;
      #pragma unroll
      for (int r = 0; r < 4; r++) HS[w][quad*4 + r][i*16 + col] = a[r] + bias;
    }
  }
  __syncthreads();
  const long rowbase = (long)mt*16;
  const int n0 = chunk*512 + w*128;
  #pragma unroll
  for (int p = 0; p < 8; p++){
    int row = p*2 + (lane >> 5);
    int c4 = (lane & 31)*4;
    int gc = n0 + c4;
    float4 v = *(const float4*)&HS[w][row][c4];
    if (gc + 3 < NOUT){
      *(float4*)&out[(rowbase + row)*NOUT + gc] = v;
    } else {
      float vv[4] = {v.x, v.y, v.z, v.w};
      #pragma unroll
      for (int k2 = 0; k2 < 4; k2++)
        if (gc + k2 < NOUT) out[(rowbase + row)*NOUT + gc + k2] = vv[k2];
    }
  }
}

// ---------------------------------------------------------------------------
extern "C" void kernel_launch(void* const* d_in, const int* in_sizes, int n_in,
                              void* d_out, int out_size, void* d_ws, size_t ws_size,
                              hipStream_t stream){
  const int*   prod = (const int*)  d_in[0];
  const int*   cat  = (const int*)  d_in[1];
  const float* age  = (const float*)d_in[2];
  const float* ts   = (const float*)d_in[3];
  const float* gen  = (const float*)d_in[4];
  const float* embp = (const float*)d_in[5];
  const float* embc = (const float*)d_in[6];
  const float* Wts  = (const float*)d_in[7];
  const float* bts  = (const float*)d_in[8];
  const float* Wuf  = (const float*)d_in[9];
  const float* bufv = (const float*)d_in[10];
  const float* Wih0 = (const float*)d_in[11];
  const float* Whh0 = (const float*)d_in[12];
  const float* bih0 = (const float*)d_in[13];
  const float* bhh0 = (const float*)d_in[14];
  const float* Wih1 = (const float*)d_in[15];
  const float* Whh1 = (const float*)d_in[16];
  const float* bih1 = (const float*)d_in[17];
  const float* bhh1 = (const float*)d_in[18];
  const float* W1   = (const float*)d_in[19];
  const float* b1   = (const float*)d_in[20];
  const float* W2   = (const float*)d_in[21];
  const float* b2   = (const float*)d_in[22];
  float* out = (float*)d_out;

  char* ws = (char*)d_ws;
  short* ws_x    = (short*)(ws);               // xfrag: 26,214,400 B
  short* ws_w    = (short*)(ws + 26214400);    // lstm W frags: 524,288 B
  float* ws_bias = (float*)(ws + 26738688);    // [2][512] f32: 4,096 B
  short* ws_hid  = (short*)(ws + 26742784);    // hidden bf16 [1024][64]: 131,072 B
  short* ws_w2   = (short*)(ws + 26873856);    // W2 bf16 [100016][64]: 12,802,048 B

  prep_lstm_w<<<128, 256, 0, stream>>>(Wih0, Whh0, bih0, bhh0,
                                       Wih1, Whh1, bih1, bhh1, ws_w, ws_bias);
  prep_w2<<<25004, 256, 0, stream>>>(W2, ws_w2);
  features<<<3200, 256, 0, stream>>>(prod, cat, age, ts, gen, embp, embc,
                                     Wts, bts, Wuf, bufv, ws_x);
  lstm_kernel<<<64, 512, 0, stream>>>(ws_x, ws_w, ws_bias, W1, b1, ws_hid);
  head2<<<196*64, 256, 0, stream>>>(ws_hid, ws_w2, b2, out);
}